// Round 4
// baseline (638.264 us; speedup 1.0000x reference)
//
#include <hip/hip_runtime.h>
#include <hip/hip_bf16.h>

typedef unsigned int u32;
typedef unsigned short u16;

#define N_PTS 100000
#define NSAMP 16

__device__ __forceinline__ float lo2f(u32 u){ return __uint_as_float(u << 16); }
__device__ __forceinline__ float hi2f(u32 u){ return __uint_as_float(u & 0xffff0000u); }
__device__ __forceinline__ float us2f(u16 u){ return __uint_as_float(((u32)u) << 16); }

// Runtime input-dtype probe. Reads only EVEN u16 indices (= low halves if the
// buffer is fp32). fp32: low halves decode as bf16 with random exponents ->
// ~46% exceed 1024 in magnitude (mean ~29+ hits). bf16 N(0,1): zero hits.
// Must be called by ALL threads of the block (contains a barrier).
__device__ __forceinline__ bool detect_f32(const u16* __restrict__ xprobe) {
    float f = us2f(xprobe[(threadIdx.x & 63) * 2]);
    int cnt = __syncthreads_count(fabsf(f) > 1024.0f ? 1 : 0);
    return cnt >= 8;
}

// canonical fp32 weight-block offsets (floats, each 16B-aligned)
#define OFF_WQ   0
#define OFF_BQ   4096
#define OFF_WK   4160
#define OFF_BK   8256
#define OFF_WV   8320
#define OFF_BV   12416
#define OFF_WP1  12480
#define OFF_BP1  12492
#define OFF_GP   12496
#define OFF_BP   12500
#define OFF_WP2  12504
#define OFF_BP2  12696
#define OFF_G1   12760
#define OFF_BB1  12824
#define OFF_WA   12888
#define OFF_BA   13400
#define OFF_G2   13408
#define OFF_BB2  13416
#define OFF_WB   13424
#define OFF_BW   13488
#define CW_PAD   16384   /* pad region to 64 KB of floats */

// ---------------------------------------------------------------------------
// K0: canonicalize all small weight arrays to fp32 (handles bf16 or fp32 src)
// ---------------------------------------------------------------------------
__global__ __launch_bounds__(256) void convert_kernel(
    const u16* __restrict__ xprobe,
    const void* s0,  const void* s1,  const void* s2,  const void* s3,
    const void* s4,  const void* s5,  const void* s6,  const void* s7,
    const void* s8,  const void* s9,  const void* s10, const void* s11,
    const void* s12, const void* s13, const void* s14, const void* s15,
    const void* s16, const void* s17, const void* s18, const void* s19,
    float* __restrict__ cw)
{
    bool isf32 = detect_f32(xprobe);
    const void* srcs[20] = {s0,s1,s2,s3,s4,s5,s6,s7,s8,s9,s10,s11,s12,s13,s14,s15,s16,s17,s18,s19};
    const int sizes[20] = {4096,64,4096,64,4096,64,9,3,3,3,192,64,64,64,512,8,8,8,64,8};
    const int offs[20]  = {OFF_WQ,OFF_BQ,OFF_WK,OFF_BK,OFF_WV,OFF_BV,OFF_WP1,OFF_BP1,OFF_GP,OFF_BP,
                           OFF_WP2,OFF_BP2,OFF_G1,OFF_BB1,OFF_WA,OFF_BA,OFF_G2,OFF_BB2,OFF_WB,OFF_BW};
    int tid = threadIdx.x + blockIdx.x * 256;
    int stride = gridDim.x * 256;
    for (int a = 0; a < 20; a++) {
        const void* s = srcs[a];
        for (int k = tid; k < sizes[a]; k += stride)
            cw[offs[a] + k] = isf32 ? ((const float*)s)[k] : us2f(((const u16*)s)[k]);
    }
}

// ---------------------------------------------------------------------------
// K1: Q = x@Wq+bq ; K = x@Wk+bk ; V = x@Wv+bv  (fp32 accum & staging)
// thread = (row, col); three flat [N][64] fp32 outputs.
// ---------------------------------------------------------------------------
__global__ __launch_bounds__(256) void qkv_kernel(
    const u16* __restrict__ xraw, const float* __restrict__ cw,
    float* __restrict__ Q, float* __restrict__ K, float* __restrict__ V)
{
    bool isf32 = detect_f32(xraw);
    int gid = blockIdx.x * 256 + threadIdx.x;   // grid = N*64 exactly
    int row = gid >> 6;
    int c   = gid & 63;
    const float* wq = cw + OFF_WQ + c;   // row-major W[k][c]: stride 64
    const float* wk = cw + OFF_WK + c;
    const float* wv = cw + OFF_WV + c;
    float aq = cw[OFF_BQ + c], ak = cw[OFF_BK + c], av = cw[OFF_BV + c];

    if (isf32) {
        const float4* xp = (const float4*)((const float*)xraw + (size_t)row * 64);
#pragma unroll 4
        for (int t = 0; t < 16; t++) {
            float4 f = xp[t];
            int k0 = 4 * t * 64;
            aq = fmaf(f.x, wq[k0],       aq); ak = fmaf(f.x, wk[k0],       ak); av = fmaf(f.x, wv[k0],       av);
            aq = fmaf(f.y, wq[k0 + 64],  aq); ak = fmaf(f.y, wk[k0 + 64],  ak); av = fmaf(f.y, wv[k0 + 64],  av);
            aq = fmaf(f.z, wq[k0 + 128], aq); ak = fmaf(f.z, wk[k0 + 128], ak); av = fmaf(f.z, wv[k0 + 128], av);
            aq = fmaf(f.w, wq[k0 + 192], aq); ak = fmaf(f.w, wk[k0 + 192], ak); av = fmaf(f.w, wv[k0 + 192], av);
        }
    } else {
        const u32* xp = (const u32*)(xraw + (size_t)row * 64);
#pragma unroll 8
        for (int t = 0; t < 32; t++) {
            u32 u = xp[t];
            float x0 = lo2f(u), x1 = hi2f(u);
            int k0 = 2 * t * 64;
            aq = fmaf(x0, wq[k0],      aq); ak = fmaf(x0, wk[k0],      ak); av = fmaf(x0, wv[k0],      av);
            aq = fmaf(x1, wq[k0 + 64], aq); ak = fmaf(x1, wk[k0 + 64], ak); av = fmaf(x1, wv[k0 + 64], av);
        }
    }
    Q[(size_t)row * 64 + c] = aq;
    K[(size_t)row * 64 + c] = ak;
    V[(size_t)row * 64 + c] = av;
}

// ---------------------------------------------------------------------------
// K2: SIMPLE fused attention. One 64-thread block (1 wave) per point.
// Lane = channel c. All cross-channel reductions go through LDS with
// barriers — no shuffles, no packing. Reference-shaped, auditable.
// ---------------------------------------------------------------------------
__global__ __launch_bounds__(64) void attn_simple_kernel(
    const u16* __restrict__ P, const int* __restrict__ IDX,
    const u16* __restrict__ xprobe, const float* __restrict__ cw,
    const float* __restrict__ Q, const float* __restrict__ K,
    const float* __restrict__ V, void* __restrict__ OUT)
{
    __shared__ float wvbuf[NSAMP * 65];   // relu(bn1(w)) per (n, c), stride 65
    __shared__ float pvbuf[NSAMP * 65];   // v + pe per (n, c)
    __shared__ float tbbuf[NSAMP * 8];    // relu(bn2(. @ Wa + ba)) per (n, s)
    __shared__ float w2buf[NSAMP * 8];    // logits, then softmax weights (n, t)

    bool isf32 = detect_f32(xprobe);

    const int i = blockIdx.x;             // point index; grid = N_PTS
    const int c = threadIdx.x;            // channel 0..63
    const float rs = 1.0f / sqrtf(1.0f + 1e-5f);

    // per-lane channel constants
    const float wp2c0 = cw[OFF_WP2 + 0 * 64 + c];
    const float wp2c1 = cw[OFF_WP2 + 1 * 64 + c];
    const float wp2c2 = cw[OFF_WP2 + 2 * 64 + c];
    const float bp2c  = cw[OFF_BP2 + c];
    const float g1c   = cw[OFF_G1  + c] * rs;
    const float bb1c  = cw[OFF_BB1 + c];
    // pos-MLP hidden layer, BN folded (same values in every lane)
    float wp1f[9], bp1f[3];
#pragma unroll
    for (int d = 0; d < 3; d++) {
        float gd = cw[OFF_GP + d] * rs;
#pragma unroll
        for (int e = 0; e < 3; e++) wp1f[e * 3 + d] = cw[OFF_WP1 + e * 3 + d] * gd;
        bp1f[d] = cw[OFF_BP1 + d] * gd + cw[OFF_BP + d];
    }

    const float* Pf = (const float*)P;
    float pi0, pi1, pi2;
    if (isf32) { pi0 = Pf[i*3+0]; pi1 = Pf[i*3+1]; pi2 = Pf[i*3+2]; }
    else       { pi0 = us2f(P[i*3+0]); pi1 = us2f(P[i*3+1]); pi2 = us2f(P[i*3+2]); }

    const float qq = Q[(size_t)i * 64 + c];

    // ---- stage 1: per-(n,c) relation input + value+pe into LDS ----
    for (int n = 0; n < NSAMP; n++) {
        const int j = IDX[i * NSAMP + n];
        float pr0, pr1, pr2;
        if (isf32) {
            pr0 = Pf[j*3+0] - pi0; pr1 = Pf[j*3+1] - pi1; pr2 = Pf[j*3+2] - pi2;
        } else {
            pr0 = us2f(P[j*3+0]) - pi0; pr1 = us2f(P[j*3+1]) - pi1; pr2 = us2f(P[j*3+2]) - pi2;
        }
        float h0 = fmaxf(fmaf(pr2, wp1f[6], fmaf(pr1, wp1f[3], fmaf(pr0, wp1f[0], bp1f[0]))), 0.0f);
        float h1 = fmaxf(fmaf(pr2, wp1f[7], fmaf(pr1, wp1f[4], fmaf(pr0, wp1f[1], bp1f[1]))), 0.0f);
        float h2 = fmaxf(fmaf(pr2, wp1f[8], fmaf(pr1, wp1f[5], fmaf(pr0, wp1f[2], bp1f[2]))), 0.0f);
        float pe = fmaf(h2, wp2c2, fmaf(h1, wp2c1, fmaf(h0, wp2c0, bp2c)));
        float kk = K[(size_t)j * 64 + c];
        float vv = V[(size_t)j * 64 + c];
        wvbuf[n * 65 + c] = fmaxf(fmaf(kk - qq + pe, g1c, bb1c), 0.0f);
        pvbuf[n * 65 + c] = vv + pe;
    }
    __syncthreads();

    // ---- stage 2: a[n][s] = ba[s] + sum_c wv[n][c]*Wa[c][s]; tb = relu(bn2) ----
    // 128 tasks over 64 lanes (2 each)
#pragma unroll
    for (int rep = 0; rep < 2; rep++) {
        int T = c + rep * 64;
        int n = T >> 3, s = T & 7;
        float a = cw[OFF_BA + s];
        for (int cc = 0; cc < 64; cc++)
            a = fmaf(wvbuf[n * 65 + cc], cw[OFF_WA + cc * 8 + s], a);
        tbbuf[n * 8 + s] = fmaxf(fmaf(a, cw[OFF_G2 + s] * rs, cw[OFF_BB2 + s]), 0.0f);
    }
    __syncthreads();

    // ---- stage 3: logits w2[n][t] = bw[t] + sum_s tb[n][s]*Wb[s][t] ----
#pragma unroll
    for (int rep = 0; rep < 2; rep++) {
        int T = c + rep * 64;
        int n = T >> 3, t = T & 7;
        float w2 = cw[OFF_BW + t];
#pragma unroll
        for (int s = 0; s < 8; s++)
            w2 = fmaf(tbbuf[n * 8 + s], cw[OFF_WB + s * 8 + t], w2);
        w2buf[n * 8 + t] = w2;
    }
    __syncthreads();

    // ---- stage 4: softmax over neighbors per attention channel t (lanes 0..7) ----
    if (c < 8) {
        float mx = -1e30f;
#pragma unroll
        for (int n = 0; n < NSAMP; n++) mx = fmaxf(mx, w2buf[n * 8 + c]);
        float sm = 0.0f;
        float e[NSAMP];
#pragma unroll
        for (int n = 0; n < NSAMP; n++) { e[n] = __expf(w2buf[n * 8 + c] - mx); sm += e[n]; }
        float inv = 1.0f / sm;
#pragma unroll
        for (int n = 0; n < NSAMP; n++) w2buf[n * 8 + c] = e[n] * inv;
    }
    __syncthreads();

    // ---- stage 5: out[c] = sum_n pv[n][c] * w[n][c&7] ----
    const int t = c & 7;
    float o = 0.0f;
#pragma unroll
    for (int n = 0; n < NSAMP; n++)
        o = fmaf(pvbuf[n * 65 + c], w2buf[n * 8 + t], o);
    if (isf32) ((float*)OUT)[(size_t)i * 64 + c] = o;
    else       ((__hip_bfloat16*)OUT)[(size_t)i * 64 + c] = __float2bfloat16(o);
}

// ---------------------------------------------------------------------------
extern "C" void kernel_launch(void* const* d_in, const int* in_sizes, int n_in,
                              void* d_out, int out_size, void* d_ws, size_t ws_size,
                              hipStream_t stream)
{
    const u16* p   = (const u16*)d_in[0];
    const u16* x   = (const u16*)d_in[1];
    const int* idx = (const int*)d_in[2];

    // workspace layout (76.9 MB — same budget rounds 2/3 ran with)
    float* cw = (float*)d_ws;                 // 64 KB (weights first: safest)
    float* Q  = cw + CW_PAD;                  // N*64 f32 = 25.6 MB
    float* K  = Q + (size_t)N_PTS * 64;       // 25.6 MB
    float* V  = K + (size_t)N_PTS * 64;       // 25.6 MB

    convert_kernel<<<8, 256, 0, stream>>>(
        x,
        d_in[3],  d_in[4],  d_in[5],  d_in[6],  d_in[7],  d_in[8],
        d_in[9],  d_in[10], d_in[11], d_in[12], d_in[13], d_in[14],
        d_in[15], d_in[16], d_in[17], d_in[18], d_in[19], d_in[20],
        d_in[21], d_in[22], cw);
    qkv_kernel<<<(N_PTS * 64) / 256, 256, 0, stream>>>(x, cw, Q, K, V);
    attn_simple_kernel<<<N_PTS, 64, 0, stream>>>(p, idx, x, cw, Q, K, V, d_out);
}

// Round 5
// 569.558 us; speedup vs baseline: 1.1206x; 1.1206x over previous
//
#include <hip/hip_runtime.h>
#include <hip/hip_bf16.h>

typedef unsigned int u32;
typedef unsigned short u16;

#define N_PTS 100000
#define NSAMP 16

__device__ __forceinline__ float lo2f(u32 u){ return __uint_as_float(u << 16); }
__device__ __forceinline__ float hi2f(u32 u){ return __uint_as_float(u & 0xffff0000u); }
__device__ __forceinline__ float us2f(u16 u){ return __uint_as_float(((u32)u) << 16); }

// Runtime input-dtype probe. Reads only EVEN u16 indices (= low halves if the
// buffer is fp32). fp32: low halves decode as bf16 with random exponents ->
// ~46% exceed 1024 in magnitude. bf16 N(0,1): zero hits.
// Must be called by ALL threads of the block (contains a barrier).
__device__ __forceinline__ bool detect_f32(const u16* __restrict__ xprobe) {
    float f = us2f(xprobe[(threadIdx.x & 63) * 2]);
    int cnt = __syncthreads_count(fabsf(f) > 1024.0f ? 1 : 0);
    return cnt >= 8;
}

// canonical fp32 weight-block offsets (floats, each 16B-aligned)
#define OFF_WQ   0
#define OFF_BQ   4096
#define OFF_WK   4160
#define OFF_BK   8256
#define OFF_WV   8320
#define OFF_BV   12416
#define OFF_WP1  12480
#define OFF_BP1  12492
#define OFF_GP   12496
#define OFF_BP   12500
#define OFF_WP2  12504
#define OFF_BP2  12696
#define OFF_G1   12760
#define OFF_BB1  12824
#define OFF_WA   12888
#define OFF_BA   13400
#define OFF_G2   13408
#define OFF_BB2  13416
#define OFF_WB   13424
#define OFF_BW   13488
#define CW_PAD   16384   /* pad region to 64 KB of floats */

// ---------------------------------------------------------------------------
// K0: canonicalize all small weight arrays to fp32 (handles bf16 or fp32 src)
// ---------------------------------------------------------------------------
__global__ __launch_bounds__(256) void convert_kernel(
    const u16* __restrict__ xprobe,
    const void* s0,  const void* s1,  const void* s2,  const void* s3,
    const void* s4,  const void* s5,  const void* s6,  const void* s7,
    const void* s8,  const void* s9,  const void* s10, const void* s11,
    const void* s12, const void* s13, const void* s14, const void* s15,
    const void* s16, const void* s17, const void* s18, const void* s19,
    float* __restrict__ cw)
{
    bool isf32 = detect_f32(xprobe);
    const void* srcs[20] = {s0,s1,s2,s3,s4,s5,s6,s7,s8,s9,s10,s11,s12,s13,s14,s15,s16,s17,s18,s19};
    const int sizes[20] = {4096,64,4096,64,4096,64,9,3,3,3,192,64,64,64,512,8,8,8,64,8};
    const int offs[20]  = {OFF_WQ,OFF_BQ,OFF_WK,OFF_BK,OFF_WV,OFF_BV,OFF_WP1,OFF_BP1,OFF_GP,OFF_BP,
                           OFF_WP2,OFF_BP2,OFF_G1,OFF_BB1,OFF_WA,OFF_BA,OFF_G2,OFF_BB2,OFF_WB,OFF_BW};
    int tid = threadIdx.x + blockIdx.x * 256;
    int stride = gridDim.x * 256;
    for (int a = 0; a < 20; a++) {
        const void* s = srcs[a];
        for (int k = tid; k < sizes[a]; k += stride)
            cw[offs[a] + k] = isf32 ? ((const float*)s)[k] : us2f(((const u16*)s)[k]);
    }
}

// ---------------------------------------------------------------------------
// K1: Q = x@Wq+bq ; K = x@Wk+bk ; V = x@Wv+bv  (fp32, register-blocked)
// Each wave handles 8 rows; lane c owns output column c of all 8 rows.
// Lane c preloads x[row][c]; x[row][k] is broadcast to the wave via __shfl,
// so each weight element is loaded once per 8 rows (24x less L1 traffic
// than the previous one-row-per-thread version).
// Block = 256 = 4 waves = 32 rows; grid = 100000/32 = 3125 exactly.
// ---------------------------------------------------------------------------
#define QKV_RPW 8
__global__ __launch_bounds__(256) void qkv_kernel(
    const u16* __restrict__ xraw, const float* __restrict__ cw,
    float* __restrict__ Q, float* __restrict__ K, float* __restrict__ V)
{
    bool isf32 = detect_f32(xraw);
    const int wid  = threadIdx.x >> 6;
    const int lane = threadIdx.x & 63;
    const int base = (blockIdx.x * 4 + wid) * QKV_RPW;
    const int c    = lane;

    float xr[QKV_RPW];
    if (isf32) {
        const float* xp = (const float*)xraw;
#pragma unroll
        for (int r = 0; r < QKV_RPW; r++)
            xr[r] = xp[(size_t)(base + r) * 64 + lane];
    } else {
#pragma unroll
        for (int r = 0; r < QKV_RPW; r++)
            xr[r] = us2f(xraw[(size_t)(base + r) * 64 + lane]);
    }

    float aq[QKV_RPW], ak[QKV_RPW], av[QKV_RPW];
    const float bqc = cw[OFF_BQ + c], bkc = cw[OFF_BK + c], bvc = cw[OFF_BV + c];
#pragma unroll
    for (int r = 0; r < QKV_RPW; r++) { aq[r] = bqc; ak[r] = bkc; av[r] = bvc; }

#pragma unroll 16
    for (int k = 0; k < 64; k++) {
        float wqk = cw[OFF_WQ + k * 64 + c];
        float wkk = cw[OFF_WK + k * 64 + c];
        float wvk = cw[OFF_WV + k * 64 + c];
#pragma unroll
        for (int r = 0; r < QKV_RPW; r++) {
            float xv = __shfl(xr[r], k, 64);
            aq[r] = fmaf(xv, wqk, aq[r]);
            ak[r] = fmaf(xv, wkk, ak[r]);
            av[r] = fmaf(xv, wvk, av[r]);
        }
    }
#pragma unroll
    for (int r = 0; r < QKV_RPW; r++) {
        Q[(size_t)(base + r) * 64 + c] = aq[r];
        K[(size_t)(base + r) * 64 + c] = ak[r];
        V[(size_t)(base + r) * 64 + c] = av[r];
    }
}

// ---------------------------------------------------------------------------
// K2: fused attention. 256-thread block = 4 waves = 4 points (one wave per
// point, pt = tid>>6) to escape the 16-workgroup/CU cap. Lane = channel c.
// Same trusted per-wave logic as the passing round-4 kernel, with two
// mechanical changes: pv kept in registers (was pvbuf LDS), and stage 2
// reads wvbuf as float4 (stride 68). Grid = 25000 exactly.
// ---------------------------------------------------------------------------
__global__ __launch_bounds__(256) void attn_kernel(
    const u16* __restrict__ P, const int* __restrict__ IDX,
    const u16* __restrict__ xprobe, const float* __restrict__ cw,
    const float* __restrict__ Q, const float* __restrict__ K,
    const float* __restrict__ V, void* __restrict__ OUT)
{
    __shared__ __align__(16) float wvbuf[4][NSAMP * 68];  // relu(bn1(w)), stride 68
    __shared__ __align__(16) float tbbuf[4][NSAMP * 8];   // relu(bn2(.@Wa+ba))
    __shared__ __align__(16) float w2buf[4][NSAMP * 8];   // logits -> softmax wts

    bool isf32 = detect_f32(xprobe);

    const int pt = threadIdx.x >> 6;
    const int c  = threadIdx.x & 63;
    const int i  = blockIdx.x * 4 + pt;        // grid*4 == N_PTS exactly
    const float rs = 1.0f / sqrtf(1.0f + 1e-5f);

    // per-lane channel constants
    const float wp2c0 = cw[OFF_WP2 + 0 * 64 + c];
    const float wp2c1 = cw[OFF_WP2 + 1 * 64 + c];
    const float wp2c2 = cw[OFF_WP2 + 2 * 64 + c];
    const float bp2c  = cw[OFF_BP2 + c];
    const float g1c   = cw[OFF_G1  + c] * rs;
    const float bb1c  = cw[OFF_BB1 + c];
    float wp1f[9], bp1f[3];
#pragma unroll
    for (int d = 0; d < 3; d++) {
        float gd = cw[OFF_GP + d] * rs;
#pragma unroll
        for (int e = 0; e < 3; e++) wp1f[e * 3 + d] = cw[OFF_WP1 + e * 3 + d] * gd;
        bp1f[d] = cw[OFF_BP1 + d] * gd + cw[OFF_BP + d];
    }

    const float* Pf = (const float*)P;
    float pi0, pi1, pi2;
    if (isf32) { pi0 = Pf[i*3+0]; pi1 = Pf[i*3+1]; pi2 = Pf[i*3+2]; }
    else       { pi0 = us2f(P[i*3+0]); pi1 = us2f(P[i*3+1]); pi2 = us2f(P[i*3+2]); }

    const float qq = Q[(size_t)i * 64 + c];
    float pv[NSAMP];

    // ---- stage 1: per-(n,c) relation input into LDS; v+pe kept in regs ----
#pragma unroll
    for (int n = 0; n < NSAMP; n++) {
        const int j = IDX[i * NSAMP + n];
        float pr0, pr1, pr2;
        if (isf32) {
            pr0 = Pf[j*3+0] - pi0; pr1 = Pf[j*3+1] - pi1; pr2 = Pf[j*3+2] - pi2;
        } else {
            pr0 = us2f(P[j*3+0]) - pi0; pr1 = us2f(P[j*3+1]) - pi1; pr2 = us2f(P[j*3+2]) - pi2;
        }
        float h0 = fmaxf(fmaf(pr2, wp1f[6], fmaf(pr1, wp1f[3], fmaf(pr0, wp1f[0], bp1f[0]))), 0.0f);
        float h1 = fmaxf(fmaf(pr2, wp1f[7], fmaf(pr1, wp1f[4], fmaf(pr0, wp1f[1], bp1f[1]))), 0.0f);
        float h2 = fmaxf(fmaf(pr2, wp1f[8], fmaf(pr1, wp1f[5], fmaf(pr0, wp1f[2], bp1f[2]))), 0.0f);
        float pe = fmaf(h2, wp2c2, fmaf(h1, wp2c1, fmaf(h0, wp2c0, bp2c)));
        float kk = K[(size_t)j * 64 + c];
        float vv = V[(size_t)j * 64 + c];
        wvbuf[pt][n * 68 + c] = fmaxf(fmaf(kk - qq + pe, g1c, bb1c), 0.0f);
        pv[n] = vv + pe;
    }
    __syncthreads();

    // ---- stage 2: a[n][s] = ba[s] + sum_c wv[n][c]*Wa[c][s]; tb = relu(bn2) ----
#pragma unroll
    for (int rep = 0; rep < 2; rep++) {
        int T = c + rep * 64;
        int n = T >> 3, s = T & 7;
        float a = cw[OFF_BA + s];
#pragma unroll
        for (int c4 = 0; c4 < 16; c4++) {
            float4 w4 = *((const float4*)&wvbuf[pt][n * 68 + c4 * 4]);
            a = fmaf(w4.x, cw[OFF_WA + (c4 * 4 + 0) * 8 + s], a);
            a = fmaf(w4.y, cw[OFF_WA + (c4 * 4 + 1) * 8 + s], a);
            a = fmaf(w4.z, cw[OFF_WA + (c4 * 4 + 2) * 8 + s], a);
            a = fmaf(w4.w, cw[OFF_WA + (c4 * 4 + 3) * 8 + s], a);
        }
        tbbuf[pt][n * 8 + s] = fmaxf(fmaf(a, cw[OFF_G2 + s] * rs, cw[OFF_BB2 + s]), 0.0f);
    }
    __syncthreads();

    // ---- stage 3: logits w2[n][t] = bw[t] + sum_s tb[n][s]*Wb[s][t] ----
#pragma unroll
    for (int rep = 0; rep < 2; rep++) {
        int T = c + rep * 64;
        int n = T >> 3, t = T & 7;
        float w2 = cw[OFF_BW + t];
#pragma unroll
        for (int s = 0; s < 8; s++)
            w2 = fmaf(tbbuf[pt][n * 8 + s], cw[OFF_WB + s * 8 + t], w2);
        w2buf[pt][n * 8 + t] = w2;
    }
    __syncthreads();

    // ---- stage 4: softmax over neighbors per attention channel t (lanes 0..7) ----
    if (c < 8) {
        float mx = -1e30f;
#pragma unroll
        for (int n = 0; n < NSAMP; n++) mx = fmaxf(mx, w2buf[pt][n * 8 + c]);
        float sm = 0.0f;
        float e[NSAMP];
#pragma unroll
        for (int n = 0; n < NSAMP; n++) { e[n] = __expf(w2buf[pt][n * 8 + c] - mx); sm += e[n]; }
        float inv = 1.0f / sm;
#pragma unroll
        for (int n = 0; n < NSAMP; n++) w2buf[pt][n * 8 + c] = e[n] * inv;
    }
    __syncthreads();

    // ---- stage 5: out[c] = sum_n pv[n] * w[n][c&7] ----
    const int t = c & 7;
    float o = 0.0f;
#pragma unroll
    for (int n = 0; n < NSAMP; n++)
        o = fmaf(pv[n], w2buf[pt][n * 8 + t], o);
    if (isf32) ((float*)OUT)[(size_t)i * 64 + c] = o;
    else       ((__hip_bfloat16*)OUT)[(size_t)i * 64 + c] = __float2bfloat16(o);
}

// ---------------------------------------------------------------------------
extern "C" void kernel_launch(void* const* d_in, const int* in_sizes, int n_in,
                              void* d_out, int out_size, void* d_ws, size_t ws_size,
                              hipStream_t stream)
{
    const u16* p   = (const u16*)d_in[0];
    const u16* x   = (const u16*)d_in[1];
    const int* idx = (const int*)d_in[2];

    // workspace layout (76.9 MB — proven safe)
    float* cw = (float*)d_ws;                 // 64 KB
    float* Q  = cw + CW_PAD;                  // N*64 f32 = 25.6 MB
    float* K  = Q + (size_t)N_PTS * 64;       // 25.6 MB
    float* V  = K + (size_t)N_PTS * 64;       // 25.6 MB

    convert_kernel<<<8, 256, 0, stream>>>(
        x,
        d_in[3],  d_in[4],  d_in[5],  d_in[6],  d_in[7],  d_in[8],
        d_in[9],  d_in[10], d_in[11], d_in[12], d_in[13], d_in[14],
        d_in[15], d_in[16], d_in[17], d_in[18], d_in[19], d_in[20],
        d_in[21], d_in[22], cw);
    qkv_kernel<<<3125, 256, 0, stream>>>(x, cw, Q, K, V);     // 3125*32 = 100000
    attn_kernel<<<N_PTS / 4, 256, 0, stream>>>(p, idx, x, cw, Q, K, V, d_out);
}